// Round 5
// baseline (12799.524 us; speedup 1.0000x reference)
//
#include <hip/hip_runtime.h>
#include <cstdint>
#include <cstddef>

#define NB 32
#define NT 2048
#define ND 256
#define NH 256
#define NG 1024   // 4*H
#define ROWS 16   // bt-rows per block in zx_kernel

#define BPB 16    // batches per rec block
#define TPB 512   // 8 waves

typedef _Float16 f16x8 __attribute__((ext_vector_type(8)));
typedef float    f32x4 __attribute__((ext_vector_type(4)));

__device__ __forceinline__ float sigf(float x) {
    return 1.0f / (1.0f + __expf(-x));
}
__device__ __forceinline__ float tanh_fast(float x) {
    return 2.0f / (1.0f + __expf(-2.0f * x)) - 1.0f;
}

// ---------------------------------------------------------------------------
// Phase 1: ZXp[t][b][p] = sum_k X[b,t,k]*Wi[k,col] + bias[col],
// stored PERMUTED: p = (col&7)*128 + (col>>3)  (wave-sliced layout for rec).
__global__ __launch_bounds__(256) void zx_kernel(const float* __restrict__ X,
                                                 const float* __restrict__ Wi,
                                                 const float* __restrict__ bias,
                                                 float* __restrict__ ZXp) {
    __shared__ float xs[ROWS][ND];
    const int tid = threadIdx.x;
    const size_t row0 = (size_t)blockIdx.x * ROWS;   // 16 consecutive bt rows (same b)
    const int b  = (int)(row0 >> 11);                // NT = 2048
    const int t0 = (int)(row0 & 2047);

    const float4* Xv = (const float4*)(X + row0 * ND);
    float4* xsv = (float4*)(&xs[0][0]);
#pragma unroll
    for (int i = 0; i < (ROWS * ND / 4) / 256; ++i)
        xsv[tid + i * 256] = Xv[tid + i * 256];
    __syncthreads();

    const int j0 = tid * 4;
    const float4 bv = *(const float4*)(bias + j0);
    float acc[ROWS][4];
#pragma unroll
    for (int r = 0; r < ROWS; ++r) {
        acc[r][0] = bv.x; acc[r][1] = bv.y; acc[r][2] = bv.z; acc[r][3] = bv.w;
    }

    for (int k = 0; k < ND; ++k) {
        const float4 w = *(const float4*)(Wi + (size_t)k * NG + j0);
#pragma unroll
        for (int r = 0; r < ROWS; ++r) {
            const float x = xs[r][k];
            acc[r][0] = fmaf(x, w.x, acc[r][0]);
            acc[r][1] = fmaf(x, w.y, acc[r][1]);
            acc[r][2] = fmaf(x, w.z, acc[r][2]);
            acc[r][3] = fmaf(x, w.w, acc[r][3]);
        }
    }

#pragma unroll
    for (int r = 0; r < ROWS; ++r) {
        const size_t base = ((size_t)(t0 + r) * NB + b) * NG;
#pragma unroll
        for (int q = 0; q < 4; ++q) {
            const int col = j0 + q;
            ZXp[base + ((col & 7) << 7) + (col >> 3)] = acc[r][q];
        }
    }
}

// ---------------------------------------------------------------------------
// Phase 2: MFMA recurrence. 2 blocks x 16 batches, 512 threads (8 waves).
// Wave w owns output cols ≡ w (mod 8): 8 N-tiles x 8 K-tiles of 16x16x32 f16.
// B-frags: kt 0..5 register-resident (192 VGPR), kt 6..7 in LDS (128 KB).
// Gate (i,f,g,o) of a unit live in the SAME lane across acc tiles -> gate
// math is register-local; h broadcast via 8 KB swizzled-f16 LDS.
__global__ __launch_bounds__(TPB)
__attribute__((amdgpu_waves_per_eu(2, 2)))
void rec_mfma(const float* __restrict__ ZXp,
              const float* __restrict__ Wh,
              const int* __restrict__ lengths,
              float* __restrict__ out)
{
    __shared__ f16x8 lwb[2][8][8][64];                       // 128 KB: [kt-6][w][nt][lane]
    __shared__ _Float16 __attribute__((aligned(16))) hsh[16 * 256];  // 8 KB, XOR-swizzled

    const int tid = threadIdx.x;
    const int l   = tid & 63;
    const int w   = tid >> 6;          // wave id = col-class (mod 8)
    const int cc  = l & 15;            // tile col / lane row-class
    const int g   = l >> 4;            // lane group
    const int bk  = blockIdx.x;

    // ---- one-time B-fragment staging (A and B share kf(g,j) = 8g+j) ----
    const int gcolb = 8 * cc + w;      // + 128*nt = global col for this lane
    f16x8 breg[6][8];
#pragma unroll
    for (int kt = 0; kt < 8; ++kt) {
#pragma unroll
        for (int nt = 0; nt < 8; ++nt) {
            f16x8 f;
#pragma unroll
            for (int j = 0; j < 8; ++j)
                f[j] = (_Float16)Wh[(size_t)(32 * kt + 8 * g + j) * NG + 128 * nt + gcolb];
            if (kt < 6) breg[kt][nt] = f;
            else        lwb[kt - 6][w][nt][l] = f;
        }
    }

    // h = 0
    for (int i = tid; i < 16 * 256; i += TPB) hsh[i] = (_Float16)0.0f;

    // per-lane batches: r = 4*g + j ; snapshot times
    int tsn[4];
    {
#pragma unroll
        for (int j = 0; j < 4; ++j) {
            const int L = lengths[bk * BPB + 4 * g + j];
            tsn[j] = (L <= 1) ? 0 : (L - 1);
        }
    }
    // block-uniform step count
    int steps = 1;
    for (int r = 0; r < BPB; ++r) {
        const int L = lengths[bk * BPB + r];
        steps = (L > steps) ? L : steps;
    }

    float c_st[2][4];
#pragma unroll
    for (int ti = 0; ti < 2; ++ti)
#pragma unroll
        for (int j = 0; j < 4; ++j) c_st[ti][j] = 0.0f;

    __syncthreads();   // staging visible (full drain OK once)

    // ZX addressing: acc[nt][j] <- ZXp[t*NB*NG + (bk*16+4g+j)*NG + w*128 + 16*nt + cc]
    const size_t base0 = (size_t)(bk * BPB + 4 * g) * NG + (size_t)w * 128 + cc;

    // prologue: preload z_x(t=0) into the MFMA C operand
    f32x4 acc[8];
#pragma unroll
    for (int nt = 0; nt < 8; ++nt)
#pragma unroll
        for (int j = 0; j < 4; ++j)
            acc[nt][j] = ZXp[base0 + (size_t)j * NG + nt * 16];

    for (int t = 0; t < steps; ++t) {
        // ---- MFMA phase: z = zx + h @ Wh ----
#pragma unroll
        for (int kt = 0; kt < 8; ++kt) {
            const f16x8 av = *(const f16x8*)(hsh + cc * 256 + (((4 * kt + g) ^ (cc & 7)) << 3));
            if (kt < 6) {
#pragma unroll
                for (int nt = 0; nt < 8; ++nt)
                    acc[nt] = __builtin_amdgcn_mfma_f32_16x16x32_f16(av, breg[kt][nt], acc[nt], 0, 0, 0);
            } else {
#pragma unroll
                for (int nt = 0; nt < 8; ++nt) {
                    const f16x8 bv = lwb[kt - 6][w][nt][l];
                    acc[nt] = __builtin_amdgcn_mfma_f32_16x16x32_f16(av, bv, acc[nt], 0, 0, 0);
                }
            }
        }

        // ---- gate phase (register-local) + reload acc with zx(t+1) ----
        const int tnext = (t + 1 < steps) ? (t + 1) : t;
        const size_t ztb = (size_t)tnext * (NB * NG) + base0;
        float hn[2][4];
#pragma unroll
        for (int j = 0; j < 4; ++j) {
            const float iv0 = acc[0][j], fv0 = acc[2][j], gv0 = acc[4][j], ov0 = acc[6][j];
            const float iv1 = acc[1][j], fv1 = acc[3][j], gv1 = acc[5][j], ov1 = acc[7][j];
            // issue next-step zx loads early (hidden under exp math + barriers)
            const float* zb = ZXp + ztb + (size_t)j * NG;
#pragma unroll
            for (int nt = 0; nt < 8; ++nt) acc[nt][j] = zb[nt * 16];

            c_st[0][j] = sigf(fv0) * c_st[0][j] + sigf(iv0) * tanh_fast(gv0);
            hn[0][j]   = sigf(ov0) * tanh_fast(c_st[0][j]);
            c_st[1][j] = sigf(fv1) * c_st[1][j] + sigf(iv1) * tanh_fast(gv1);
            hn[1][j]   = sigf(ov1) * tanh_fast(c_st[1][j]);

            if (t == tsn[j]) {
                const size_t ob = (size_t)(bk * BPB + 4 * g + j) * NH;
                out[ob +   8 * cc + w]        = hn[0][j];
                out[ob + 128 + 8 * cc + w]    = hn[1][j];
            }
        }

        // all waves done reading hsh (A-frags consumed by MFMA) -> safe to write
        __builtin_amdgcn_s_barrier();
        __builtin_amdgcn_sched_barrier(0);
#pragma unroll
        for (int ti = 0; ti < 2; ++ti)
#pragma unroll
            for (int j = 0; j < 4; ++j) {
                const int r  = 4 * g + j;
                const int kb = 16 * ti + cc;          // u>>3 ; u&7 == w
                hsh[r * 256 + ((kb ^ (r & 7)) << 3) + w] = (_Float16)hn[ti][j];
            }
        // LDS writes visible, WITHOUT draining vmcnt (zx prefetch stays in flight)
        asm volatile("s_waitcnt lgkmcnt(0)" ::: "memory");
        __builtin_amdgcn_sched_barrier(0);
        __builtin_amdgcn_s_barrier();
        __builtin_amdgcn_sched_barrier(0);
    }
}

// ---------------------------------------------------------------------------
// Fallback recurrence (streams weights; used only if ws can't hold ZXp)
__global__ __launch_bounds__(512) void rec_fallback(
    const float* __restrict__ X,
    const float* __restrict__ Wi,
    const float* __restrict__ Wh,
    const float* __restrict__ bias,
    const int* __restrict__ lengths,
    float* __restrict__ out)
{
    __shared__ float hs[NH];
    __shared__ float zs[NG];
    __shared__ float xs[ND];

    const int b   = blockIdx.x;
    const int tid = threadIdx.x;
    const int c0  = tid * 2;

    const int len   = lengths[b];
    const int steps = (len < 1) ? 1 : len;

    float c_state = 0.0f;
    if (tid < NH) hs[tid] = 0.0f;
    const float b0 = bias[c0], b1 = bias[c0 + 1];
    __syncthreads();

    for (int t = 0; t < steps; ++t) {
        float a0 = b0, a1 = b1;
        if (tid < ND) xs[tid] = X[((size_t)b * NT + t) * ND + tid];
        __syncthreads();
#pragma unroll 2
        for (int k = 0; k < ND; k += 4) {
            const float4 xv = *(const float4*)(xs + k);
            const float2 w0 = *(const float2*)(Wi + (size_t)(k + 0) * NG + c0);
            const float2 w1 = *(const float2*)(Wi + (size_t)(k + 1) * NG + c0);
            const float2 w2 = *(const float2*)(Wi + (size_t)(k + 2) * NG + c0);
            const float2 w3 = *(const float2*)(Wi + (size_t)(k + 3) * NG + c0);
            a0 = fmaf(xv.x, w0.x, a0); a1 = fmaf(xv.x, w0.y, a1);
            a0 = fmaf(xv.y, w1.x, a0); a1 = fmaf(xv.y, w1.y, a1);
            a0 = fmaf(xv.z, w2.x, a0); a1 = fmaf(xv.z, w2.y, a1);
            a0 = fmaf(xv.w, w3.x, a0); a1 = fmaf(xv.w, w3.y, a1);
        }
#pragma unroll 2
        for (int k = 0; k < NH; k += 4) {
            const float4 hv = *(const float4*)(hs + k);
            const float2 w0 = *(const float2*)(Wh + (size_t)(k + 0) * NG + c0);
            const float2 w1 = *(const float2*)(Wh + (size_t)(k + 1) * NG + c0);
            const float2 w2 = *(const float2*)(Wh + (size_t)(k + 2) * NG + c0);
            const float2 w3 = *(const float2*)(Wh + (size_t)(k + 3) * NG + c0);
            a0 = fmaf(hv.x, w0.x, a0); a1 = fmaf(hv.x, w0.y, a1);
            a0 = fmaf(hv.y, w1.x, a0); a1 = fmaf(hv.y, w1.y, a1);
            a0 = fmaf(hv.z, w2.x, a0); a1 = fmaf(hv.z, w2.y, a1);
            a0 = fmaf(hv.w, w3.x, a0); a1 = fmaf(hv.w, w3.y, a1);
        }

        float2 zo2; zo2.x = a0; zo2.y = a1;
        *(float2*)(zs + c0) = zo2;
        __syncthreads();

        if (tid < NH) {
            const float iv = zs[tid];
            const float fv = zs[NH + tid];
            const float gv = zs[2 * NH + tid];
            const float ov = zs[3 * NH + tid];
            c_state = sigf(fv) * c_state + sigf(iv) * tanh_fast(gv);
            hs[tid] = sigf(ov) * tanh_fast(c_state);
        }
        __syncthreads();
    }

    if (tid < NH) out[(size_t)b * NH + tid] = hs[tid];
}

extern "C" void kernel_launch(void* const* d_in, const int* in_sizes, int n_in,
                              void* d_out, int out_size, void* d_ws, size_t ws_size,
                              hipStream_t stream) {
    const float* X       = (const float*)d_in[0];
    const int*   lengths = (const int*)d_in[1];
    const float* Wi      = (const float*)d_in[2];
    const float* Wh      = (const float*)d_in[3];
    const float* bias    = (const float*)d_in[4];
    float* out = (float*)d_out;

    const size_t zx_bytes = (size_t)NB * NT * NG * sizeof(float);  // 256 MB
    float* ZXp = (float*)d_ws;

    if (ws_size >= zx_bytes) {
        zx_kernel<<<dim3((NB * NT) / ROWS), dim3(256), 0, stream>>>(X, Wi, bias, ZXp);
        rec_mfma<<<dim3(NB / BPB), dim3(TPB), 0, stream>>>(ZXp, Wh, lengths, out);
    } else {
        rec_fallback<<<dim3(NB), dim3(512), 0, stream>>>(X, Wi, Wh, bias, lengths, out);
    }
}

// Round 6
// 4553.288 us; speedup vs baseline: 2.8111x; 2.8111x over previous
//
#include <hip/hip_runtime.h>
#include <cstdint>
#include <cstddef>

#define NB 32
#define NT 2048
#define ND 256
#define NH 256
#define NG 1024   // 4*H
#define ROWS 16   // bt-rows per block in zx_kernel

#define RTPB 1024          // 16 waves, 4/EU -> 128 arch-VGPR budget
#define RKL  64            // k-values with weights in LDS (8 uint4 rows = 128 KB)
#define RNQ  96            // f16 packs per column in regs: (256-RKL)/2

typedef _Float16 h2_t __attribute__((ext_vector_type(2)));

__device__ __forceinline__ float sigf(float x) {
    return 1.0f / (1.0f + __expf(-x));
}
__device__ __forceinline__ float tanh_fast(float x) {
    return 2.0f / (1.0f + __expf(-2.0f * x)) - 1.0f;
}

__device__ __forceinline__ h2_t as_h2(uint32_t u) {
    union { uint32_t u; h2_t h; } c; c.u = u; return c.h;
}
__device__ __forceinline__ uint32_t packf16(float a, float b) {
    union { uint32_t u; h2_t h; } c;
    c.h[0] = (_Float16)a; c.h[1] = (_Float16)b;
    return c.u;
}
__device__ __forceinline__ float dot2(uint32_t hpack, uint32_t wpack, float acc) {
    return __builtin_amdgcn_fdot2(as_h2(hpack), as_h2(wpack), acc, false);
}

// ---------------------------------------------------------------------------
// Phase 1: ZX[bt][j] = sum_k X[bt][k] * Wi[k][j] + bias[j]  (plain layout)
__global__ __launch_bounds__(256) void zx_kernel(const float* __restrict__ X,
                                                 const float* __restrict__ Wi,
                                                 const float* __restrict__ bias,
                                                 float* __restrict__ ZX) {
    __shared__ float xs[ROWS][ND];
    const int tid = threadIdx.x;
    const size_t row0 = (size_t)blockIdx.x * ROWS;

    const float4* Xv = (const float4*)(X + row0 * ND);
    float4* xsv = (float4*)(&xs[0][0]);
#pragma unroll
    for (int i = 0; i < (ROWS * ND / 4) / 256; ++i)
        xsv[tid + i * 256] = Xv[tid + i * 256];
    __syncthreads();

    const int j0 = tid * 4;
    const float4 bv = *(const float4*)(bias + j0);
    float acc[ROWS][4];
#pragma unroll
    for (int r = 0; r < ROWS; ++r) {
        acc[r][0] = bv.x; acc[r][1] = bv.y; acc[r][2] = bv.z; acc[r][3] = bv.w;
    }

    for (int k = 0; k < ND; ++k) {
        const float4 w = *(const float4*)(Wi + (size_t)k * NG + j0);
#pragma unroll
        for (int r = 0; r < ROWS; ++r) {
            const float x = xs[r][k];
            acc[r][0] = fmaf(x, w.x, acc[r][0]);
            acc[r][1] = fmaf(x, w.y, acc[r][1]);
            acc[r][2] = fmaf(x, w.z, acc[r][2]);
            acc[r][3] = fmaf(x, w.w, acc[r][3]);
        }
    }

#pragma unroll
    for (int r = 0; r < ROWS; ++r) {
        float4 o;
        o.x = acc[r][0]; o.y = acc[r][1]; o.z = acc[r][2]; o.w = acc[r][3];
        *(float4*)(ZX + (row0 + r) * NG + j0) = o;
    }
}

// ---------------------------------------------------------------------------
// Phase 2: persistent-weight recurrence. One block per batch, 1024 threads
// (16 waves, 4/EU). Thread j owns gate column j. Wh packed f16:
//   k = 0..RKL-1  -> LDS uint4 rows (128 KB), lane-contiguous b128 reads
//   k = RKL..255  -> RNQ=96 packs/thread: fits the 128-VGPR budget honestly
// (rounds 2/4/5 showed demand >128 V triggers remat/AGPR-overflow; 96+~25
// working regs stays under, so weights remain truly register-resident).
__global__ __launch_bounds__(RTPB)
void rec_pers(const float* __restrict__ ZX,
              const float* __restrict__ Wh,
              const int* __restrict__ lengths,
              float* __restrict__ out)
{
    __shared__ uint4 lw[RKL / 8][RTPB];            // 128 KB
    __shared__ float zs[NG];                       // 4 KB
    __shared__ __align__(16) _Float16 hs_h[NH];    // 512 B

    const int b = blockIdx.x;
    const int j = threadIdx.x;                     // gate column 0..1023

    // ---- one-time staging (coalesced over j at fixed k) ----
#pragma unroll
    for (int r = 0; r < RKL / 8; ++r) {
        const int k = 8 * r;
        uint4 p;
        p.x = packf16(Wh[(size_t)(k + 0) * NG + j], Wh[(size_t)(k + 1) * NG + j]);
        p.y = packf16(Wh[(size_t)(k + 2) * NG + j], Wh[(size_t)(k + 3) * NG + j]);
        p.z = packf16(Wh[(size_t)(k + 4) * NG + j], Wh[(size_t)(k + 5) * NG + j]);
        p.w = packf16(Wh[(size_t)(k + 6) * NG + j], Wh[(size_t)(k + 7) * NG + j]);
        lw[r][j] = p;
    }

    uint32_t wq[RNQ];
#pragma unroll
    for (int q = 0; q < RNQ; ++q) {
        const int k = RKL + 2 * q;
        wq[q] = packf16(Wh[(size_t)k * NG + j], Wh[(size_t)(k + 1) * NG + j]);
    }

    if (j < NH) hs_h[j] = (_Float16)0.0f;
    float c = 0.0f, hlast = 0.0f;
    __syncthreads();

    const int len   = lengths[b];
    const int steps = (len < 1) ? 1 : len;         // idx = max(0,len-1) -> idx+1 steps

    for (int t = 0; t < steps; ++t) {
        // issue early; consumed only at zs write (~1 us of dot work hides latency)
        const float zx = ZX[((size_t)b * NT + t) * NG + j];

        float a0 = 0.0f, a1 = 0.0f;

        // k = 0..RKL-1: weights from LDS (b128, lane-contiguous: conflict-free)
#pragma unroll
        for (int r = 0; r < RKL / 8; ++r) {
            const uint4 h4 = *(const uint4*)(hs_h + 8 * r);   // broadcast
            const uint4 p  = lw[r][j];
            a0 = dot2(h4.x, p.x, a0); a1 = dot2(h4.y, p.y, a1);
            a0 = dot2(h4.z, p.z, a0); a1 = dot2(h4.w, p.w, a1);
        }

        // k = RKL..255: register-resident weights
#pragma unroll
        for (int m = 0; m < RNQ / 4; ++m) {
            const uint4 h4 = *(const uint4*)(hs_h + RKL + 8 * m);  // broadcast
            a0 = dot2(h4.x, wq[4 * m + 0], a0);
            a1 = dot2(h4.y, wq[4 * m + 1], a1);
            a0 = dot2(h4.z, wq[4 * m + 2], a0);
            a1 = dot2(h4.w, wq[4 * m + 3], a1);
        }

        zs[j] = zx + a0 + a1;
        __syncthreads();                            // zs complete

        if (j < NH) {                               // wave-uniform branch (waves 0-3)
            const float iv = zs[j];
            const float fv = zs[NH + j];
            const float gv = zs[2 * NH + j];
            const float ov = zs[3 * NH + j];
            c = sigf(fv) * c + sigf(iv) * tanh_fast(gv);
            hlast = sigf(ov) * tanh_fast(c);
            hs_h[j] = (_Float16)hlast;
        }
        __syncthreads();                            // new h visible
    }

    if (j < NH) out[(size_t)b * NH + j] = hlast;
}

// ---------------------------------------------------------------------------
// Fallback recurrence (streams weights; used only if ws can't hold ZX)
__global__ __launch_bounds__(512) void rec_fallback(
    const float* __restrict__ X,
    const float* __restrict__ Wi,
    const float* __restrict__ Wh,
    const float* __restrict__ bias,
    const int* __restrict__ lengths,
    float* __restrict__ out)
{
    __shared__ float hs[NH];
    __shared__ float zs[NG];
    __shared__ float xs[ND];

    const int b   = blockIdx.x;
    const int tid = threadIdx.x;
    const int c0  = tid * 2;

    const int len   = lengths[b];
    const int steps = (len < 1) ? 1 : len;

    float c_state = 0.0f;
    if (tid < NH) hs[tid] = 0.0f;
    const float b0 = bias[c0], b1 = bias[c0 + 1];
    __syncthreads();

    for (int t = 0; t < steps; ++t) {
        float a0 = b0, a1 = b1;
        if (tid < ND) xs[tid] = X[((size_t)b * NT + t) * ND + tid];
        __syncthreads();
#pragma unroll 2
        for (int k = 0; k < ND; k += 4) {
            const float4 xv = *(const float4*)(xs + k);
            const float2 w0 = *(const float2*)(Wi + (size_t)(k + 0) * NG + c0);
            const float2 w1 = *(const float2*)(Wi + (size_t)(k + 1) * NG + c0);
            const float2 w2 = *(const float2*)(Wi + (size_t)(k + 2) * NG + c0);
            const float2 w3 = *(const float2*)(Wi + (size_t)(k + 3) * NG + c0);
            a0 = fmaf(xv.x, w0.x, a0); a1 = fmaf(xv.x, w0.y, a1);
            a0 = fmaf(xv.y, w1.x, a0); a1 = fmaf(xv.y, w1.y, a1);
            a0 = fmaf(xv.z, w2.x, a0); a1 = fmaf(xv.z, w2.y, a1);
            a0 = fmaf(xv.w, w3.x, a0); a1 = fmaf(xv.w, w3.y, a1);
        }
#pragma unroll 2
        for (int k = 0; k < NH; k += 4) {
            const float4 hv = *(const float4*)(hs + k);
            const float2 w0 = *(const float2*)(Wh + (size_t)(k + 0) * NG + c0);
            const float2 w1 = *(const float2*)(Wh + (size_t)(k + 1) * NG + c0);
            const float2 w2 = *(const float2*)(Wh + (size_t)(k + 2) * NG + c0);
            const float2 w3 = *(const float2*)(Wh + (size_t)(k + 3) * NG + c0);
            a0 = fmaf(hv.x, w0.x, a0); a1 = fmaf(hv.x, w0.y, a1);
            a0 = fmaf(hv.y, w1.x, a0); a1 = fmaf(hv.y, w1.y, a1);
            a0 = fmaf(hv.z, w2.x, a0); a1 = fmaf(hv.z, w2.y, a1);
            a0 = fmaf(hv.w, w3.x, a0); a1 = fmaf(hv.w, w3.y, a1);
        }

        float2 zo2; zo2.x = a0; zo2.y = a1;
        *(float2*)(zs + c0) = zo2;
        __syncthreads();

        if (tid < NH) {
            const float iv = zs[tid];
            const float fv = zs[NH + tid];
            const float gv = zs[2 * NH + tid];
            const float ov = zs[3 * NH + tid];
            c_state = sigf(fv) * c_state + sigf(iv) * tanh_fast(gv);
            hs[tid] = sigf(ov) * tanh_fast(c_state);
        }
        __syncthreads();
    }

    if (tid < NH) out[(size_t)b * NH + tid] = hs[tid];
}

extern "C" void kernel_launch(void* const* d_in, const int* in_sizes, int n_in,
                              void* d_out, int out_size, void* d_ws, size_t ws_size,
                              hipStream_t stream) {
    const float* X       = (const float*)d_in[0];
    const int*   lengths = (const int*)d_in[1];
    const float* Wi      = (const float*)d_in[2];
    const float* Wh      = (const float*)d_in[3];
    const float* bias    = (const float*)d_in[4];
    float* out = (float*)d_out;

    const size_t zx_bytes = (size_t)NB * NT * NG * sizeof(float);  // 256 MB
    float* ZX = (float*)d_ws;

    if (ws_size >= zx_bytes) {
        zx_kernel<<<dim3((NB * NT) / ROWS), dim3(256), 0, stream>>>(X, Wi, bias, ZX);
        rec_pers<<<dim3(NB), dim3(RTPB), 0, stream>>>(ZX, Wh, lengths, out);
    } else {
        rec_fallback<<<dim3(NB), dim3(512), 0, stream>>>(X, Wi, Wh, bias, lengths, out);
    }
}